// Round 2
// baseline (454.629 us; speedup 1.0000x reference)
//
#include <hip/hip_runtime.h>

#define H_IMG 1024
#define W_IMG 1024
#define N_IMG 16
#define C_IMG 3
#define PPT   4   // pixels per thread (consecutive in w; 4 | 1024 so same row)

__global__ __launch_bounds__(256) void homography_warp_kernel(
    const float* __restrict__ img,   // [N, 3, H, W]
    const float* __restrict__ homo,  // [N, 3, 3]
    float* __restrict__ out)         // [N, 3, H, W]
{
    const int n    = blockIdx.y;
    const int tid  = blockIdx.x * 256 + threadIdx.x;
    const int pix0 = tid * PPT;                // first of 4 consecutive pixels
    const int h    = pix0 >> 10;               // W_IMG == 1024
    const int w0   = pix0 & (W_IMG - 1);

    // Block-uniform homography coefficients -> scalar loads
    const float* Hm = homo + n * 9;
    const float h00 = Hm[0], h01 = Hm[1], h02 = Hm[2];
    const float h10 = Hm[3], h11 = Hm[4], h12 = Hm[5];
    const float h20 = Hm[6], h21 = Hm[7], h22 = Hm[8];

    const float gy = fmaf((float)h, 2.0f / (H_IMG - 1), -1.0f);
    // fold the gy-dependent terms once
    const float ax = fmaf(h01, gy, h02);
    const float ay = fmaf(h11, gy, h12);
    const float az = fmaf(h21, gy, h22);

    int   off[PPT][4];   // linear gather offsets per pixel, 4 corners
    float wt [PPT][4];   // bilinear weights with zeros-padding validity folded in

#pragma unroll
    for (int j = 0; j < PPT; ++j) {
        const float gx = fmaf((float)(w0 + j), 2.0f / (W_IMG - 1), -1.0f);
        const float tx = fmaf(h00, gx, ax);
        const float ty = fmaf(h10, gx, ay);
        const float tz = fmaf(h20, gx, az);
        const float inv = __builtin_amdgcn_rcpf(tz);   // ~1ulp rcp, plenty for 9e-2 tol
        const float xp = fmaf(tx * inv, 511.5f, 511.5f);  // (u+1)*0.5*(W-1)
        const float yp = fmaf(ty * inv, 511.5f, 511.5f);

        const float x0f = floorf(xp);
        const float y0f = floorf(yp);
        const float fx = xp - x0f;
        const float fy = yp - y0f;

        const int ix0 = (int)x0f;
        const int iy0 = (int)y0f;
        const int ix1 = ix0 + 1;
        const int iy1 = iy0 + 1;

        const float vx0 = (ix0 >= 0 && ix0 < W_IMG) ? 1.0f : 0.0f;
        const float vx1 = (ix1 >= 0 && ix1 < W_IMG) ? 1.0f : 0.0f;
        const float vy0 = (iy0 >= 0 && iy0 < H_IMG) ? 1.0f : 0.0f;
        const float vy1 = (iy1 >= 0 && iy1 < H_IMG) ? 1.0f : 0.0f;

        wt[j][0] = (1.0f - fx) * (1.0f - fy) * vx0 * vy0;
        wt[j][1] = fx * (1.0f - fy) * vx1 * vy0;
        wt[j][2] = (1.0f - fx) * fy * vx0 * vy1;
        wt[j][3] = fx * fy * vx1 * vy1;

        const int cx0 = min(max(ix0, 0), W_IMG - 1);
        const int cx1 = min(max(ix1, 0), W_IMG - 1);
        const int cy0 = min(max(iy0, 0), H_IMG - 1);
        const int cy1 = min(max(iy1, 0), H_IMG - 1);

        off[j][0] = cy0 * W_IMG + cx0;
        off[j][1] = cy0 * W_IMG + cx1;
        off[j][2] = cy1 * W_IMG + cx0;
        off[j][3] = cy1 * W_IMG + cx1;
    }

    const size_t plane = (size_t)H_IMG * W_IMG;
    const size_t base  = (size_t)n * C_IMG * plane;

#pragma unroll
    for (int c = 0; c < C_IMG; ++c) {
        const float* __restrict__ p = img + base + (size_t)c * plane;

        // Issue all 16 independent gathers before any use -> deep vmcnt pipeline
        float v[PPT][4];
#pragma unroll
        for (int j = 0; j < PPT; ++j)
#pragma unroll
            for (int k = 0; k < 4; ++k)
                v[j][k] = p[off[j][k]];

        float4 r;
        r.x = wt[0][0]*v[0][0] + wt[0][1]*v[0][1] + wt[0][2]*v[0][2] + wt[0][3]*v[0][3];
        r.y = wt[1][0]*v[1][0] + wt[1][1]*v[1][1] + wt[1][2]*v[1][2] + wt[1][3]*v[1][3];
        r.z = wt[2][0]*v[2][0] + wt[2][1]*v[2][1] + wt[2][2]*v[2][2] + wt[2][3]*v[2][3];
        r.w = wt[3][0]*v[3][0] + wt[3][1]*v[3][1] + wt[3][2]*v[3][2] + wt[3][3]*v[3][3];

        *(float4*)(out + base + (size_t)c * plane + (size_t)pix0) = r;
    }
}

extern "C" void kernel_launch(void* const* d_in, const int* in_sizes, int n_in,
                              void* d_out, int out_size, void* d_ws, size_t ws_size,
                              hipStream_t stream) {
    const float* img  = (const float*)d_in[0];   // patch_src   [16,3,1024,1024]
    const float* homo = (const float*)d_in[1];   // dst_homo_src [16,3,3]
    float* o = (float*)d_out;                    // [16,3,1024,1024] fp32

    dim3 block(256);
    dim3 grid((H_IMG * W_IMG) / (256 * PPT), N_IMG);
    homography_warp_kernel<<<grid, block, 0, stream>>>(img, homo, o);
}

// Round 3
// 380.454 us; speedup vs baseline: 1.1950x; 1.1950x over previous
//
#include <hip/hip_runtime.h>

#define H_IMG 1024
#define W_IMG 1024
#define N_IMG 16
#define C_IMG 3
#define RPT   4   // rows per thread (vertical stacking preserves lane-consecutive w!)

__global__ __launch_bounds__(256) void homography_warp_kernel(
    const float* __restrict__ img,   // [N, 3, H, W]
    const float* __restrict__ homo,  // [N, 3, 3]
    float* __restrict__ out)         // [N, 3, H, W]
{
    const int n  = blockIdx.y;
    // w-major tiling: adjacent blocks share image rows (L2 locality)
    const int col_tile = blockIdx.x & 3;          // W/256 = 4 tiles across
    const int row_tile = blockIdx.x >> 2;         // H/RPT = 256 row-tiles
    const int w  = col_tile * 256 + threadIdx.x;  // lane-consecutive w (DO NOT change)
    const int h0 = row_tile * RPT;

    // Block-uniform homography coefficients -> scalar loads
    const float* Hm = homo + n * 9;
    const float h00 = Hm[0], h01 = Hm[1], h02 = Hm[2];
    const float h10 = Hm[3], h11 = Hm[4], h12 = Hm[5];
    const float h20 = Hm[6], h21 = Hm[7], h22 = Hm[8];

    // gx is shared by all RPT rows of this thread -> fold gx-terms once
    const float gx = fmaf((float)w, 2.0f / (W_IMG - 1), -1.0f);
    const float bx = fmaf(h00, gx, h02);
    const float by = fmaf(h10, gx, h12);
    const float bz = fmaf(h20, gx, h22);

    int   off[RPT][4];   // linear gather offsets, 4 corners per row
    float wt [RPT][4];   // bilinear weights with zeros-padding validity folded in

#pragma unroll
    for (int r = 0; r < RPT; ++r) {
        const float gy = fmaf((float)(h0 + r), 2.0f / (H_IMG - 1), -1.0f);
        const float tx = fmaf(h01, gy, bx);
        const float ty = fmaf(h11, gy, by);
        const float tz = fmaf(h21, gy, bz);
        const float inv = __builtin_amdgcn_rcpf(tz);     // ~1ulp, tol is 9.2e-2
        const float xp = fmaf(tx * inv, 511.5f, 511.5f); // (u+1)*0.5*(W-1)
        const float yp = fmaf(ty * inv, 511.5f, 511.5f);

        const float x0f = floorf(xp);
        const float y0f = floorf(yp);
        const float fx = xp - x0f;
        const float fy = yp - y0f;

        const int ix0 = (int)x0f;
        const int iy0 = (int)y0f;
        const int ix1 = ix0 + 1;
        const int iy1 = iy0 + 1;

        const float vx0 = (ix0 >= 0 && ix0 < W_IMG) ? 1.0f : 0.0f;
        const float vx1 = (ix1 >= 0 && ix1 < W_IMG) ? 1.0f : 0.0f;
        const float vy0 = (iy0 >= 0 && iy0 < H_IMG) ? 1.0f : 0.0f;
        const float vy1 = (iy1 >= 0 && iy1 < H_IMG) ? 1.0f : 0.0f;

        wt[r][0] = (1.0f - fx) * (1.0f - fy) * vx0 * vy0;
        wt[r][1] = fx * (1.0f - fy) * vx1 * vy0;
        wt[r][2] = (1.0f - fx) * fy * vx0 * vy1;
        wt[r][3] = fx * fy * vx1 * vy1;

        const int cx0 = min(max(ix0, 0), W_IMG - 1);
        const int cx1 = min(max(ix1, 0), W_IMG - 1);
        const int cy0 = min(max(iy0, 0), H_IMG - 1);
        const int cy1 = min(max(iy1, 0), H_IMG - 1);

        off[r][0] = cy0 * W_IMG + cx0;
        off[r][1] = cy0 * W_IMG + cx1;
        off[r][2] = cy1 * W_IMG + cx0;
        off[r][3] = cy1 * W_IMG + cx1;
    }

    const size_t plane = (size_t)H_IMG * W_IMG;
    const size_t base  = (size_t)n * C_IMG * plane;
    const size_t opix0 = (size_t)h0 * W_IMG + (size_t)w;

#pragma unroll
    for (int c = 0; c < C_IMG; ++c) {
        const float* __restrict__ p = img + base + (size_t)c * plane;

        // 16 independent gathers issued before ANY use -> deep vmcnt pipeline.
        // Each instruction is lane-coalesced (consecutive w across lanes).
        float v[RPT][4];
#pragma unroll
        for (int r = 0; r < RPT; ++r)
#pragma unroll
            for (int k = 0; k < 4; ++k)
                v[r][k] = p[off[r][k]];

        float* __restrict__ po = out + base + (size_t)c * plane + opix0;
#pragma unroll
        for (int r = 0; r < RPT; ++r) {
            const float res = wt[r][0]*v[r][0] + wt[r][1]*v[r][1]
                            + wt[r][2]*v[r][2] + wt[r][3]*v[r][3];
            // nontemporal: output is never re-read; don't evict gather lines
            __builtin_nontemporal_store(res, po + (size_t)r * W_IMG);
        }
    }
}

extern "C" void kernel_launch(void* const* d_in, const int* in_sizes, int n_in,
                              void* d_out, int out_size, void* d_ws, size_t ws_size,
                              hipStream_t stream) {
    const float* img  = (const float*)d_in[0];   // patch_src    [16,3,1024,1024]
    const float* homo = (const float*)d_in[1];   // dst_homo_src [16,3,3]
    float* o = (float*)d_out;                    // [16,3,1024,1024] fp32

    dim3 block(256);
    dim3 grid((W_IMG / 256) * (H_IMG / RPT), N_IMG);   // 1024 x 16
    homography_warp_kernel<<<grid, block, 0, stream>>>(img, homo, o);
}